// Round 16
// baseline (108.864 us; speedup 1.0000x reference)
//
#include <hip/hip_runtime.h>

namespace {
constexpr int NB = 64, NS = 196, ND = 64, NO = 10;
constexpr int EPAIRS = NS * ND * ND;            // 802816 (e0,e1) pairs
constexpr size_t EBYTES = (size_t)EPAIRS * 4;   // bf16 pair table

// R16: batch-parallel waves on a shared ring. Block = 4 waves = 4 batches of
// the SAME direction; shared depth-6 ring of 16KB site tiles (96KB LDS).
// etab [s][l][r]: bf16 pair (e0|e1<<16), site 16384B, row 256B (as R14).
// Step: v' = s*v + x0*A0 + x1*A1 per batch, v fp32 in per-wave vbuf; E bf16.
// Staging split 4 ways: wave w issues 4 gload_lds (1KB) per site (its quarter).
// Sync per step: {WAITV(20) own-loads; BAR -> whole tile visible; COMP;
// BAR -> all read; ISSUE next site into freed slot}. No cross-wave data dep.
// All in-loop LDS ops are inline asm; counted vmcnt only; drained tail.

typedef unsigned u32x4 __attribute__((ext_vector_type(4)));
typedef float f32x4v __attribute__((ext_vector_type(4)));
typedef float f32x2v __attribute__((ext_vector_type(2)));

typedef const __attribute__((address_space(1))) void* gasp_t;
typedef __attribute__((address_space(3))) void* lasp_t;
typedef __attribute__((address_space(3))) char* lcp_t;

#define LDSOFF(p) ((unsigned)(unsigned long long)(lcp_t)(void*)(p))
#define SB0() __builtin_amdgcn_sched_barrier(0)
#define WAITV(N) do { asm volatile("s_waitcnt vmcnt(" #N ")" ::: "memory"); SB0(); } while (0)
#define LGKM0() do { asm volatile("s_waitcnt lgkmcnt(0)" ::: "memory"); SB0(); } while (0)
#define BAR()   do { asm volatile("s_barrier" ::: "memory"); } while (0)
#define GL2LDS(g, l) __builtin_amdgcn_global_load_lds((gasp_t)(const void*)(g), (lasp_t)(void*)(l), 16, 0, 0)

#define RD4O(d, b, off) asm volatile("ds_read_b128 %0, %1 offset:%c2" : "=v"(d) : "v"(b), "i"(off))
#define RD2O(d, b, off) asm volatile("ds_read_b64 %0, %1 offset:%c2"  : "=v"(d) : "v"(b), "i"(off))
#define WR4(b, v4)      asm volatile("ds_write_b128 %0, %1" :: "v"(b), "v"(v4))
#define WR1(b, v1)      asm volatile("ds_write_b32 %0, %1" :: "v"(b), "v"(v1))

#define U0(w_) __builtin_bit_cast(float, (unsigned)((w_) << 16))
#define U1(w_) __builtin_bit_cast(float, (unsigned)((w_) & 0xFFFF0000u))

#define REP16_(M) M(0) M(1) M(2) M(3) M(4) M(5) M(6) M(7) M(8) M(9) M(10) M(11) M(12) M(13) M(14) M(15)

// ---- staging: wave w stages its quarter (4x 1KB) of site SITE into SLOT ----
#define LISSUE(SLOT, SITE) do {                                               \
  const char* _g = etab + (size_t)(SITE) * 16384 + w4k + lane * 16;           \
  char* _l = tbc + (SLOT) * 16384 + w4k;                                      \
  GL2LDS(_g, _l); GL2LDS(_g + 1024, _l + 1024);                               \
  GL2LDS(_g + 2048, _l + 2048); GL2LDS(_g + 3072, _l + 3072);                 \
} while (0)

#define RISSUE(SLOT, SITE) do {                                               \
  const char* _g = etab + (size_t)(SITE) * 16384 + w4k;                       \
  char* _l = tbc + (SLOT) * 16384 + w4k;                                      \
  GL2LDS(_g + vrp[0], _l);        GL2LDS(_g + 1024 + vrp[1], _l + 1024);      \
  GL2LDS(_g + 2048 + vrp[0], _l + 2048);                                      \
  GL2LDS(_g + 3072 + vrp[1], _l + 3072);                                      \
} while (0)

// ---- left compute (R14 macros, per-wave vbuf, slot base folded at runtime) ----
#define LT_(i) RD4O(tt[i], lbc, (i) * 256);
#define LF_(i) { const float vi = vv[(i) >> 2][(i) & 3];                      \
  { const unsigned W = tt[i][0]; a00 = fmaf(vi, U0(W), a00); a10 = fmaf(vi, U1(W), a10); } \
  { const unsigned W = tt[i][1]; a01 = fmaf(vi, U0(W), a01); a11 = fmaf(vi, U1(W), a11); } \
  { const unsigned W = tt[i][2]; a02 = fmaf(vi, U0(W), a02); a12 = fmaf(vi, U1(W), a12); } \
  { const unsigned W = tt[i][3]; a03 = fmaf(vi, U0(W), a03); a13 = fmaf(vi, U1(W), a13); } }

#define LCOMP(SLOT, XC) do {                                                  \
  const unsigned lbc = lbL + (SLOT) * 16384u;                                 \
  u32x4 tt[16]; f32x4v vv[4];                                                 \
  RD4O(vv[0], vlB, 0);  RD4O(vv[1], vlB, 16);                                 \
  RD4O(vv[2], vlB, 32); RD4O(vv[3], vlB, 48);                                 \
  REP16_(LT_)                                                                 \
  LGKM0();                                                                    \
  float a00 = 0.f, a01 = 0.f, a02 = 0.f, a03 = 0.f;                           \
  float a10 = 0.f, a11 = 0.f, a12 = 0.f, a13 = 0.f;                           \
  REP16_(LF_)                                                                 \
  a00 += __shfl_xor(a00, 16, 64); a00 += __shfl_xor(a00, 32, 64);             \
  a01 += __shfl_xor(a01, 16, 64); a01 += __shfl_xor(a01, 32, 64);             \
  a02 += __shfl_xor(a02, 16, 64); a02 += __shfl_xor(a02, 32, 64);             \
  a03 += __shfl_xor(a03, 16, 64); a03 += __shfl_xor(a03, 32, 64);             \
  a10 += __shfl_xor(a10, 16, 64); a10 += __shfl_xor(a10, 32, 64);             \
  a11 += __shfl_xor(a11, 16, 64); a11 += __shfl_xor(a11, 32, 64);             \
  a12 += __shfl_xor(a12, 16, 64); a12 += __shfl_xor(a12, 32, 64);             \
  a13 += __shfl_xor(a13, 16, 64); a13 += __shfl_xor(a13, 32, 64);             \
  const float s0_ = (XC).x + (XC).y;                                          \
  y0 = fmaf(s0_, y0, fmaf((XC).x, a00, (XC).y * a10));                        \
  y1 = fmaf(s0_, y1, fmaf((XC).x, a01, (XC).y * a11));                        \
  y2 = fmaf(s0_, y2, fmaf((XC).x, a02, (XC).y * a12));                        \
  y3 = fmaf(s0_, y3, fmaf((XC).x, a03, (XC).y * a13));                        \
  if (q == 0) { f32x4v yv_; yv_[0] = y0; yv_[1] = y1; yv_[2] = y2;            \
                yv_[3] = y3; WR4(vwL, yv_); }                                 \
} while (0)

// ---- right compute (R14 macros, per-wave vbuf) ----
#define RU_(m) RD4O(vv[m], vwB, (m) * 16);
#define RT_(g) RD4O(tt[g], rbc[(g) & 7], (((g) & 8) ? 128 : 0));
#define RF_(g) {                                                              \
  { const float v_ = vv[g][0]; const unsigned W = tt[g][0];                   \
    a00 = fmaf(v_, U0(W), a00); a10 = fmaf(v_, U1(W), a10); }                 \
  { const float v_ = vv[g][1]; const unsigned W = tt[g][1];                   \
    a01 = fmaf(v_, U0(W), a01); a11 = fmaf(v_, U1(W), a11); }                 \
  { const float v_ = vv[g][2]; const unsigned W = tt[g][2];                   \
    a02 = fmaf(v_, U0(W), a02); a12 = fmaf(v_, U1(W), a12); }                 \
  { const float v_ = vv[g][3]; const unsigned W = tt[g][3];                   \
    a03 = fmaf(v_, U0(W), a03); a13 = fmaf(v_, U1(W), a13); } }

#define RCOMP(SLOT, XC) do {                                                  \
  unsigned rbc[8];                                                            \
  _Pragma("unroll") for (int m = 0; m < 8; ++m)                               \
    rbc[m] = rbR[m] + (SLOT) * 16384u;                                        \
  u32x4 tt[16]; f32x4v vv[16];                                                \
  REP16_(RU_)                                                                 \
  REP16_(RT_)                                                                 \
  LGKM0();                                                                    \
  float a00 = 0.f, a01 = 0.f, a02 = 0.f, a03 = 0.f;                           \
  float a10 = 0.f, a11 = 0.f, a12 = 0.f, a13 = 0.f;                           \
  REP16_(RF_)                                                                 \
  const float s0_ = (XC).x + (XC).y;                                          \
  yr = fmaf(s0_, yr, fmaf((XC).x, (a00 + a01) + (a02 + a03),                  \
                          (XC).y * ((a10 + a11) + (a12 + a13))));             \
  WR1(vwR, yr);                                                               \
} while (0)

// step: x-read -> own-WAITV -> BAR(tile visible) -> COMP -> BAR(all read) -> ISSUE
#define LSTEP(SLOT, XOFF, WN, ISS) do {                                       \
  f32x2v xc; RD2O(xc, xsb, XOFF);                                             \
  WAITV(WN); BAR();                                                           \
  LCOMP(SLOT, xc);                                                            \
  BAR(); ISS;                                                                 \
} while (0)

#define RSTEP(SLOT, XOFF, WN, ISS) do {                                       \
  f32x2v xc; RD2O(xc, xsb, XOFF);                                             \
  WAITV(WN); BAR();                                                           \
  RCOMP(SLOT, xc);                                                            \
  BAR(); ISS;                                                                 \
} while (0)

__device__ __forceinline__ unsigned bf16rne(float f) {
    const unsigned b = __builtin_bit_cast(unsigned, f);
    return (b + 0x7FFFu + ((b >> 16) & 1u)) >> 16;
}

__global__ __launch_bounds__(256) void mps_conv_kernel(
    const float* __restrict__ cores, char* __restrict__ etab)
{
    const int p = blockIdx.x * 256 + threadIdx.x;
    const int rem = p & 4095;
    const int l = rem >> 6, r = rem & 63;
    const float2 c = ((const float2*)cores)[p];
    const float sub = (l == r) ? 1.0f : 0.0f;
    ((unsigned*)etab)[p] = bf16rne(c.x - sub) | (bf16rne(c.y - sub) << 16);
}

__global__ __launch_bounds__(256, 1) void mps_chain_kernel(
    const float* __restrict__ x,      // [B][S][2]
    const char* __restrict__ etab,    // bf16 E table
    float* __restrict__ wsv)          // [B][2][64]
{
    __shared__ __align__(16) char tiles[6 * 16384];    // 96KB shared ring
    __shared__ __align__(16) float vbuf[4][ND];        // per-wave fp32 vector
    __shared__ __align__(16) float xlds[4 * NS * 2];   // 4 batches' x

    const int bid  = blockIdx.x;
    const int dir  = bid & 1;          // 0 = left, 1 = right
    const int grp  = bid >> 1;         // 16 groups of 4 batches
    const int tid  = threadIdx.x;
    const int w    = tid >> 6;
    const int lane = tid & 63;
    const int batch = grp * 4 + w;

    for (int i = tid; i < 4 * 98; i += 256) {
        const int bb = i / 98, e = i - bb * 98;
        ((float4*)xlds)[i] = ((const float4*)x)[(grp * 4 + bb) * 98 + e];
    }
    vbuf[w][lane] = (lane == 0) ? 1.0f : 0.0f;
    __syncthreads();   // drains prologue; per-wave vmcnt baseline = 0

    char* tbc = (char*)tiles;
    const unsigned tB  = LDSOFF(tiles);
    const unsigned vwB = LDSOFF(vbuf) + (unsigned)(w * 256);
    const unsigned xw  = LDSOFF(xlds) + (unsigned)(w * 1568);
    const unsigned w4k = (unsigned)(w * 4096);

    if (!dir) {
        const int q = lane >> 4, t = lane & 15;
        const unsigned lbL = tB + (unsigned)(q * 4096 + t * 16);
        const unsigned vlB = vwB + (unsigned)(q * 64);
        const unsigned vwL = vwB + (unsigned)(t * 16);
        float y0 = (t == 0) ? 1.f : 0.f, y1 = 0.f, y2 = 0.f, y3 = 0.f;
        LISSUE(0, 0); LISSUE(1, 1); LISSUE(2, 2);
        LISSUE(3, 3); LISSUE(4, 4); LISSUE(5, 5);
        for (int s = 0; s < 90; s += 6) {
            const unsigned xsb = xw + 8u * (unsigned)s;
            LSTEP(0, 0,  20, LISSUE(0, s + 6));
            LSTEP(1, 8,  20, LISSUE(1, s + 7));
            LSTEP(2, 16, 20, LISSUE(2, s + 8));
            LSTEP(3, 24, 20, LISSUE(3, s + 9));
            LSTEP(4, 32, 20, LISSUE(4, s + 10));
            LSTEP(5, 40, 20, LISSUE(5, s + 11));
        }
        {   // steps 90..97 (sites 90..97)
            const unsigned xsb = xw + 8u * 90u;
            LSTEP(0, 0,  20, LISSUE(0, 96));
            LSTEP(1, 8,  20, LISSUE(1, 97));
            LSTEP(2, 16, 20, );
            LSTEP(3, 24, 16, );
            LSTEP(4, 32, 12, );
            LSTEP(5, 40, 8,  );
            LSTEP(0, 48, 4,  );
            LSTEP(1, 56, 0,  );
        }
        if (q == 0)
            ((float4*)(wsv + batch * 128))[t] = make_float4(y0, y1, y2, y3);
    } else {
        const int l7 = lane & 7;
        unsigned rbR[8];
        #pragma unroll
        for (int m = 0; m < 8; ++m)
            rbR[m] = tB + (unsigned)(lane * 256 + ((m ^ l7) << 4));
        unsigned vrp[2];
        #pragma unroll
        for (int par = 0; par < 2; ++par)
            vrp[par] = (unsigned)((lane >> 4) * 256
                       + (((lane & 15) ^ (4 * par + (lane >> 4))) << 4));
        const unsigned vwR = vwB + (unsigned)(lane * 4);
        float yr = (lane == 0) ? 1.f : 0.f;
        RISSUE(0, 195); RISSUE(1, 194); RISSUE(2, 193);
        RISSUE(3, 192); RISSUE(4, 191); RISSUE(5, 190);
        for (int s = 0; s < 90; s += 6) {
            const unsigned xsb = xw + 8u * (unsigned)(190 - s);
            RSTEP(0, 40, 20, RISSUE(0, 189 - s));
            RSTEP(1, 32, 20, RISSUE(1, 188 - s));
            RSTEP(2, 24, 20, RISSUE(2, 187 - s));
            RSTEP(3, 16, 20, RISSUE(3, 186 - s));
            RSTEP(4, 8,  20, RISSUE(4, 185 - s));
            RSTEP(5, 0,  20, RISSUE(5, 184 - s));
        }
        {   // steps 90..97 (sites 105..98)
            const unsigned xsb = xw + 8u * 98u;
            RSTEP(0, 56, 20, RISSUE(0, 99));
            RSTEP(1, 48, 20, RISSUE(1, 98));
            RSTEP(2, 40, 20, );
            RSTEP(3, 32, 16, );
            RSTEP(4, 24, 12, );
            RSTEP(5, 16, 8,  );
            RSTEP(0, 8,  4,  );
            RSTEP(1, 0,  0,  );
        }
        wsv[batch * 128 + 64 + lane] = yr;
    }
}

__global__ __launch_bounds__(128) void mps_out_kernel(
    const float* __restrict__ wsv,    // [B][2][64]
    const float* __restrict__ oc,     // [O][D][D]
    float* __restrict__ out)          // [B][O]
{
    __shared__ __align__(16) float lsh[ND];
    __shared__ __align__(16) float rsh[ND];
    const int b    = blockIdx.x;
    const int tid  = threadIdx.x;
    const int wave = tid >> 6;
    const int lane = tid & 63;
    if (wave == 0) lsh[lane] = wsv[b * 128 + lane];
    else           rsh[lane] = wsv[b * 128 + 64 + lane];
    __syncthreads();

    #pragma unroll
    for (int oo = 0; oo < 5; ++oo) {
        const int o = wave * 5 + oo;
        const float* ocp = oc + o * (ND * ND) + lane * ND;
        float acc = 0.f;
        #pragma unroll
        for (int t = 0; t < ND; t += 4) {
            const float4 r4 = *(const float4*)(rsh + t);
            const float4 c4 = *(const float4*)(ocp + t);
            acc = fmaf(c4.x, r4.x, acc);
            acc = fmaf(c4.y, r4.y, acc);
            acc = fmaf(c4.z, r4.z, acc);
            acc = fmaf(c4.w, r4.w, acc);
        }
        float p = lsh[lane] * acc;
        #pragma unroll
        for (int off = 32; off > 0; off >>= 1) p += __shfl_xor(p, off, 64);
        if (lane == 0) out[b * NO + o] = p;
    }
}
} // namespace

extern "C" void kernel_launch(void* const* d_in, const int* in_sizes, int n_in,
                              void* d_out, int out_size, void* d_ws, size_t ws_size,
                              hipStream_t stream) {
    const float* x     = (const float*)d_in[0];
    const float* cores = (const float*)d_in[1];
    const float* ocp   = (const float*)d_in[2];
    float* out = (float*)d_out;
    char*  etab = (char*)d_ws;
    float* wsv  = (float*)((char*)d_ws + EBYTES);
    hipLaunchKernelGGL(mps_conv_kernel,  dim3(EPAIRS / 256), dim3(256), 0, stream, cores, etab);
    hipLaunchKernelGGL(mps_chain_kernel, dim3(32),  dim3(256), 0, stream, x, etab, wsv);
    hipLaunchKernelGGL(mps_out_kernel,   dim3(NB),  dim3(128), 0, stream, wsv, ocp, out);
}

// Round 17
// 69.538 us; speedup vs baseline: 1.5655x; 1.5655x over previous
//
#include <hip/hip_runtime.h>

namespace {
constexpr int NB = 64, NS = 196, ND = 64, NO = 10;
constexpr int EPAIRS = NS * ND * ND;            // 802816 (e0,e1) u32 pairs
constexpr size_t EBYTES = (size_t)EPAIRS * 4;   // bf16 pair table

// R17: register-staged chains (NO tile LDS, NO global_load_lds).
// etab[p]: u32 = bf16(e0) | bf16(e1)<<16, p = site*4096 + l*64 + r  (E = cores - I).
// Step: v'[c] = s*v[c] + x0*A0[c] + x1*A1[c], A_i[c] = sum_l v[l] E_i[l,c]; v fp32.
// Block = one chain (batch, dir), 2 waves, 128 blocks.
//   left  (dir=0): wave w owns cols [32w,32w+32); lane (q=lane>>4,t=lane&15)
//     owns cols c0=32w+2t,c0+1 over l in [16q,16q+16): 16 x uint2 loads/site.
//   right (dir=1): wave w owns rows [32w,32w+32); lane (lr=lane>>1,h=lane&1)
//     owns row 32w+lr, r in [32h,32h+32): 8 x uint4 loads/site (contiguous).
// v ping-pong in LDS vbuf[2][64]; one asm barrier per step:
//   "s_waitcnt lgkmcnt(0); s_barrier" + "memory" clobber. This is a TWO-WAY IR
//   memory fence: the site-(s+2) prefetch loads placed inside step s cannot
//   sink past it (the R2/R3 failure was sched_barrier = IntrNoMem, no fence).
//   No vmcnt in the barrier -> in-flight register loads survive; the compiler
//   emits its own COUNTED vmcnt at first use. Prefetch distance ~1.5 steps.

#define BARRIER() asm volatile("s_waitcnt lgkmcnt(0)\n\ts_barrier" ::: "memory")

#define U0(w_) __builtin_bit_cast(float, (unsigned)((w_) << 16))
#define U1(w_) __builtin_bit_cast(float, (unsigned)((w_) & 0xFFFF0000u))

__device__ __forceinline__ unsigned bf16rne(float f) {
    const unsigned b = __builtin_bit_cast(unsigned, f);
    return (b + 0x7FFFu + ((b >> 16) & 1u)) >> 16;
}

__global__ __launch_bounds__(256) void mps_conv_kernel(
    const float* __restrict__ cores, unsigned* __restrict__ etab)
{
    const int p = blockIdx.x * 256 + threadIdx.x;
    const int rem = p & 4095;
    const int l = rem >> 6, r = rem & 63;
    const float2 c = ((const float2*)cores)[p];
    const float sub = (l == r) ? 1.0f : 0.0f;
    etab[p] = bf16rne(c.x - sub) | (bf16rne(c.y - sub) << 16);
}

// ---- left: load site into 16 x uint2 ----
#define LLOAD(BUF, SITE) do {                                                 \
  const unsigned* _p = gL + (size_t)(SITE) * 4096;                            \
  _Pragma("unroll") for (int i = 0; i < 16; ++i)                              \
    BUF[i] = *(const uint2*)(_p + i * 64);                                    \
} while (0)

// ---- left step: parity P (compile-time), buffer BUF, site S (runtime) ----
#define LSTEP(P, BUF, S) do {                                                 \
  const float2 xc = *(const float2*)(xlds + 2 * (S));                         \
  const float s0 = xc.x + xc.y;                                               \
  float4 vv[4];                                                               \
  _Pragma("unroll") for (int m = 0; m < 4; ++m)                               \
    vv[m] = ((const float4*)(vbuf[P] + 16 * q))[m];                           \
  const float2 yo = *(const float2*)(vbuf[P] + c0);                           \
  float a00a = 0.f, a10a = 0.f, a01a = 0.f, a11a = 0.f;                       \
  float a00b = 0.f, a10b = 0.f, a01b = 0.f, a11b = 0.f;                       \
  _Pragma("unroll") for (int i = 0; i < 16; i += 2) {                         \
    { const float vl = vv[i >> 2][i & 3]; const uint2 W = BUF[i];             \
      a00a = fmaf(vl, U0(W.x), a00a); a10a = fmaf(vl, U1(W.x), a10a);         \
      a01a = fmaf(vl, U0(W.y), a01a); a11a = fmaf(vl, U1(W.y), a11a); }       \
    { const float vl = vv[(i + 1) >> 2][(i + 1) & 3]; const uint2 W = BUF[i + 1]; \
      a00b = fmaf(vl, U0(W.x), a00b); a10b = fmaf(vl, U1(W.x), a10b);         \
      a01b = fmaf(vl, U0(W.y), a01b); a11b = fmaf(vl, U1(W.y), a11b); }       \
  }                                                                           \
  float a00 = a00a + a00b, a10 = a10a + a10b;                                 \
  float a01 = a01a + a01b, a11 = a11a + a11b;                                 \
  a00 += __shfl_xor(a00, 16, 64); a00 += __shfl_xor(a00, 32, 64);             \
  a10 += __shfl_xor(a10, 16, 64); a10 += __shfl_xor(a10, 32, 64);             \
  a01 += __shfl_xor(a01, 16, 64); a01 += __shfl_xor(a01, 32, 64);             \
  a11 += __shfl_xor(a11, 16, 64); a11 += __shfl_xor(a11, 32, 64);             \
  if (q == 0) {                                                               \
    float2 yn;                                                                \
    yn.x = fmaf(s0, yo.x, fmaf(xc.x, a00, xc.y * a10));                       \
    yn.y = fmaf(s0, yo.y, fmaf(xc.x, a01, xc.y * a11));                       \
    *(float2*)(vbuf[(P) ^ 1] + c0) = yn;                                      \
  }                                                                           \
} while (0)

// ---- right: load site into 8 x uint4 (contiguous 128B) ----
#define RLOAD(BUF, SITE) do {                                                 \
  const unsigned* _p = gR + (size_t)(SITE) * 4096;                            \
  _Pragma("unroll") for (int m = 0; m < 8; ++m)                               \
    BUF[m] = *(const uint4*)(_p + m * 4);                                     \
} while (0)

// ---- right step: parity P, buffer BUF, step index K (site = 195-K) ----
#define RSTEP(P, BUF, K) do {                                                 \
  const float2 xc = *(const float2*)(xlds + 2 * (195 - (K)));                 \
  const float s0 = xc.x + xc.y;                                               \
  float4 vv[8];                                                               \
  _Pragma("unroll") for (int m = 0; m < 8; ++m)                               \
    vv[m] = ((const float4*)(vbuf[P] + 32 * h))[m];                           \
  const float yo = vbuf[P][row];                                              \
  float a0a = 0.f, a1a = 0.f, a0b = 0.f, a1b = 0.f;                           \
  _Pragma("unroll") for (int m = 0; m < 8; m += 2) {                          \
    { const uint4 W = BUF[m]; const float4 V = vv[m];                         \
      a0a = fmaf(V.x, U0(W.x), a0a); a1a = fmaf(V.x, U1(W.x), a1a);           \
      a0a = fmaf(V.y, U0(W.y), a0a); a1a = fmaf(V.y, U1(W.y), a1a);           \
      a0a = fmaf(V.z, U0(W.z), a0a); a1a = fmaf(V.z, U1(W.z), a1a);           \
      a0a = fmaf(V.w, U0(W.w), a0a); a1a = fmaf(V.w, U1(W.w), a1a); }         \
    { const uint4 W = BUF[m + 1]; const float4 V = vv[m + 1];                 \
      a0b = fmaf(V.x, U0(W.x), a0b); a1b = fmaf(V.x, U1(W.x), a1b);           \
      a0b = fmaf(V.y, U0(W.y), a0b); a1b = fmaf(V.y, U1(W.y), a1b);           \
      a0b = fmaf(V.z, U0(W.z), a0b); a1b = fmaf(V.z, U1(W.z), a1b);           \
      a0b = fmaf(V.w, U0(W.w), a0b); a1b = fmaf(V.w, U1(W.w), a1b); }         \
  }                                                                           \
  float a0 = a0a + a0b, a1 = a1a + a1b;                                       \
  a0 += __shfl_xor(a0, 1, 64);                                                \
  a1 += __shfl_xor(a1, 1, 64);                                                \
  if (h == 0)                                                                 \
    vbuf[(P) ^ 1][row] = fmaf(s0, yo, fmaf(xc.x, a0, xc.y * a1));             \
} while (0)

__global__ __launch_bounds__(128, 1) void mps_chain_kernel(
    const float* __restrict__ x,        // [B][S][2]
    const unsigned* __restrict__ etab,  // bf16 pair table
    float* __restrict__ wsv)            // [B][2][64]
{
    __shared__ __align__(16) float vbuf[2][ND];
    __shared__ __align__(16) float xlds[NS * 2];

    const int bid   = blockIdx.x;
    const int batch = bid >> 1;
    const int dir   = bid & 1;          // 0 = left, 1 = right
    const int tid   = threadIdx.x;
    const int w     = tid >> 6;
    const int lane  = tid & 63;

    for (int i = tid; i < 98; i += 128)
        ((float4*)xlds)[i] = ((const float4*)(x + batch * (NS * 2)))[i];
    if (tid < 64) vbuf[0][tid] = (tid == 0) ? 1.0f : 0.0f;
    __syncthreads();

    if (!dir) {
        const int q = lane >> 4, t = lane & 15;
        const int c0 = 32 * w + 2 * t;
        const unsigned* gL = etab + 16 * q * 64 + c0;
        uint2 eA[16], eB[16];
        LLOAD(eA, 0); LLOAD(eB, 1);
        #pragma unroll 1
        for (int s = 0; s < 96; s += 2) {
            LSTEP(0, eA, s);     LLOAD(eA, s + 2); BARRIER();
            LSTEP(1, eB, s + 1); LLOAD(eB, s + 3); BARRIER();
        }
        LSTEP(0, eA, 96); BARRIER();
        LSTEP(1, eB, 97); BARRIER();
    } else {
        const int lr = lane >> 1, h = lane & 1;
        const int row = 32 * w + lr;
        const unsigned* gR = etab + row * 64 + 32 * h;
        uint4 rA[8], rB[8];
        RLOAD(rA, 195); RLOAD(rB, 194);
        #pragma unroll 1
        for (int k = 0; k < 96; k += 2) {
            RSTEP(0, rA, k);     RLOAD(rA, 193 - k); BARRIER();
            RSTEP(1, rB, k + 1); RLOAD(rB, 192 - k); BARRIER();
        }
        RSTEP(0, rA, 96); BARRIER();
        RSTEP(1, rB, 97); BARRIER();
    }
    // final vector is in vbuf[0] (step 97 wrote parity 0); barrier above synced
    if (tid < 64) wsv[batch * 128 + dir * 64 + tid] = vbuf[0][tid];
}

__global__ __launch_bounds__(128) void mps_out_kernel(
    const float* __restrict__ wsv,    // [B][2][64]
    const float* __restrict__ oc,     // [O][D][D]
    float* __restrict__ out)          // [B][O]
{
    __shared__ __align__(16) float lsh[ND];
    __shared__ __align__(16) float rsh[ND];
    const int b    = blockIdx.x;
    const int tid  = threadIdx.x;
    const int wave = tid >> 6;
    const int lane = tid & 63;
    if (wave == 0) lsh[lane] = wsv[b * 128 + lane];
    else           rsh[lane] = wsv[b * 128 + 64 + lane];
    __syncthreads();

    #pragma unroll
    for (int oo = 0; oo < 5; ++oo) {
        const int o = wave * 5 + oo;
        const float* ocp = oc + o * (ND * ND) + lane * ND;
        float acc = 0.f;
        #pragma unroll
        for (int t = 0; t < ND; t += 4) {
            const float4 r4 = *(const float4*)(rsh + t);
            const float4 c4 = *(const float4*)(ocp + t);
            acc = fmaf(c4.x, r4.x, acc);
            acc = fmaf(c4.y, r4.y, acc);
            acc = fmaf(c4.z, r4.z, acc);
            acc = fmaf(c4.w, r4.w, acc);
        }
        float p = lsh[lane] * acc;
        #pragma unroll
        for (int off = 32; off > 0; off >>= 1) p += __shfl_xor(p, off, 64);
        if (lane == 0) out[b * NO + o] = p;
    }
}
} // namespace

extern "C" void kernel_launch(void* const* d_in, const int* in_sizes, int n_in,
                              void* d_out, int out_size, void* d_ws, size_t ws_size,
                              hipStream_t stream) {
    const float* x     = (const float*)d_in[0];
    const float* cores = (const float*)d_in[1];
    const float* ocp   = (const float*)d_in[2];
    float* out = (float*)d_out;
    unsigned* etab = (unsigned*)d_ws;
    float* wsv = (float*)((char*)d_ws + EBYTES);
    hipLaunchKernelGGL(mps_conv_kernel,  dim3(EPAIRS / 256), dim3(256), 0, stream, cores, etab);
    hipLaunchKernelGGL(mps_chain_kernel, dim3(2 * NB), dim3(128), 0, stream, x, etab, wsv);
    hipLaunchKernelGGL(mps_out_kernel,   dim3(NB),     dim3(128), 0, stream, wsv, ocp, out);
}

// Round 18
// 66.360 us; speedup vs baseline: 1.6405x; 1.0479x over previous
//
#include <hip/hip_runtime.h>

namespace {
constexpr int NB = 64, NS = 196, ND = 64, NO = 10;
constexpr int EPAIRS = NS * ND * ND;            // 802816 (e0,e1) u32 pairs
constexpr size_t EBYTES = (size_t)EPAIRS * 4;   // bf16 pair table

// R18 = R17 structure with the prefetch loads PINNED as asm-volatile register
// loads (R17's compiler-visible loads were sunk: etab is const/invariant, so
// they legally crossed the memory-clobber barrier; VGPR=56 proved it).
// etab[p]: u32 = bf16(e0)|bf16(e1)<<16, p = site*4096 + l*64 + r (E = cores-I).
// Step: v' = s*v + x0*A0 + x1*A1 (v fp32; only E quantized).
// Block = one (batch, dir): 2 waves, 128 blocks.
//  left : wave w owns cols [32w,32w+32); lane (q,t): cols c0=32w+2t,c0+1,
//         l in [16q,16q+16) -> 16 asm global_load_dwordx2 per site.
//  right: wave w owns rows [32w,32w+32); lane (lr,h): row 32w+lr,
//         r in [32h,32h+32) -> 8 asm global_load_dwordx4 per site.
// Payload = 64 VGPR/wave (2 buffers) -- far from spill (R4/R5 had 256-384).
// Counted WAITV(16) before consuming a buffer (16 newer loads in flight),
// WAITV(0) in the tail = fully drained before final writes (R4 lesson).
// y carried in REGISTERS (all lanes hold the reduced sums); vbuf ping-pong
// only redistributes v; one "lgkmcnt(0); s_barrier" memory-fence per step.

#define SB0() __builtin_amdgcn_sched_barrier(0)
#define WAITV(N) do { asm volatile("s_waitcnt vmcnt(" #N ")" ::: "memory"); SB0(); } while (0)
#define BARRIER() do { asm volatile("s_waitcnt lgkmcnt(0)\n\ts_barrier" ::: "memory"); } while (0)

#define GLX2(dst, ap, IMM) \
  asm volatile("global_load_dwordx2 %0, %1, off offset:" #IMM : "=v"(dst) : "v"(ap))
#define GLX4(dst, ap, IMM) \
  asm volatile("global_load_dwordx4 %0, %1, off offset:" #IMM : "=v"(dst) : "v"(ap))

#define U0(w_) __builtin_bit_cast(float, (unsigned)((w_) << 16))
#define U1(w_) __builtin_bit_cast(float, (unsigned)((w_) & 0xFFFF0000u))

__device__ __forceinline__ unsigned bf16rne(float f) {
    const unsigned b = __builtin_bit_cast(unsigned, f);
    return (b + 0x7FFFu + ((b >> 16) & 1u)) >> 16;
}

__global__ __launch_bounds__(256) void mps_conv_kernel(
    const float* __restrict__ cores, unsigned* __restrict__ etab)
{
    const int p = blockIdx.x * 256 + threadIdx.x;
    const int rem = p & 4095;
    const int l = rem >> 6, r = rem & 63;
    const float2 c = ((const float2*)cores)[p];
    const float sub = (l == r) ? 1.0f : 0.0f;
    etab[p] = bf16rne(c.x - sub) | (bf16rne(c.y - sub) << 16);
}

// ---- left: 16 asm dwordx2, stride 256B ----
#define ALOADL(BUF, SITE) do {                                                \
  const char* _a = gLb + (size_t)(SITE) * 16384;                              \
  GLX2(BUF[0],  _a, 0);    GLX2(BUF[1],  _a, 256);                            \
  GLX2(BUF[2],  _a, 512);  GLX2(BUF[3],  _a, 768);                            \
  GLX2(BUF[4],  _a, 1024); GLX2(BUF[5],  _a, 1280);                           \
  GLX2(BUF[6],  _a, 1536); GLX2(BUF[7],  _a, 1792);                           \
  GLX2(BUF[8],  _a, 2048); GLX2(BUF[9],  _a, 2304);                           \
  GLX2(BUF[10], _a, 2560); GLX2(BUF[11], _a, 2816);                           \
  GLX2(BUF[12], _a, 3072); GLX2(BUF[13], _a, 3328);                           \
  GLX2(BUF[14], _a, 3584); GLX2(BUF[15], _a, 3840);                           \
} while (0)

// ---- right: 8 asm dwordx4, contiguous 128B ----
#define ALOADR(BUF, SITE) do {                                                \
  const char* _a = gRb + (size_t)(SITE) * 16384;                              \
  GLX4(BUF[0], _a, 0);  GLX4(BUF[1], _a, 16);                                 \
  GLX4(BUF[2], _a, 32); GLX4(BUF[3], _a, 48);                                 \
  GLX4(BUF[4], _a, 64); GLX4(BUF[5], _a, 80);                                 \
  GLX4(BUF[6], _a, 96); GLX4(BUF[7], _a, 112);                                \
} while (0)

// ---- left step (parity P): vv from vbuf[P]; y carried in registers ----
#define LSTEP(P, BUF, S) do {                                                 \
  const float2 xc = *(const float2*)(xlds + 2 * (S));                         \
  const float s0 = xc.x + xc.y;                                               \
  float4 vv[4];                                                               \
  _Pragma("unroll") for (int m = 0; m < 4; ++m)                               \
    vv[m] = ((const float4*)(vbuf[P] + 16 * q))[m];                           \
  float a00a = 0.f, a10a = 0.f, a01a = 0.f, a11a = 0.f;                       \
  float a00b = 0.f, a10b = 0.f, a01b = 0.f, a11b = 0.f;                       \
  _Pragma("unroll") for (int i = 0; i < 16; i += 2) {                         \
    { const float vl = vv[i >> 2][i & 3]; const uint2 W = BUF[i];             \
      a00a = fmaf(vl, U0(W.x), a00a); a10a = fmaf(vl, U1(W.x), a10a);         \
      a01a = fmaf(vl, U0(W.y), a01a); a11a = fmaf(vl, U1(W.y), a11a); }       \
    { const float vl = vv[(i + 1) >> 2][(i + 1) & 3]; const uint2 W = BUF[i + 1]; \
      a00b = fmaf(vl, U0(W.x), a00b); a10b = fmaf(vl, U1(W.x), a10b);         \
      a01b = fmaf(vl, U0(W.y), a01b); a11b = fmaf(vl, U1(W.y), a11b); }       \
  }                                                                           \
  float a00 = a00a + a00b, a10 = a10a + a10b;                                 \
  float a01 = a01a + a01b, a11 = a11a + a11b;                                 \
  a00 += __shfl_xor(a00, 16, 64); a00 += __shfl_xor(a00, 32, 64);             \
  a10 += __shfl_xor(a10, 16, 64); a10 += __shfl_xor(a10, 32, 64);             \
  a01 += __shfl_xor(a01, 16, 64); a01 += __shfl_xor(a01, 32, 64);             \
  a11 += __shfl_xor(a11, 16, 64); a11 += __shfl_xor(a11, 32, 64);             \
  y0r = fmaf(s0, y0r, fmaf(xc.x, a00, xc.y * a10));                           \
  y1r = fmaf(s0, y1r, fmaf(xc.x, a01, xc.y * a11));                           \
  if (q == 0) {                                                               \
    float2 yn; yn.x = y0r; yn.y = y1r;                                        \
    *(float2*)(vbuf[(P) ^ 1] + c0) = yn;                                      \
  }                                                                           \
} while (0)

// ---- right step (parity P): vv from vbuf[P]; y carried in registers ----
#define RSTEP(P, BUF, K) do {                                                 \
  const float2 xc = *(const float2*)(xlds + 2 * (195 - (K)));                 \
  const float s0 = xc.x + xc.y;                                               \
  float4 vv[8];                                                               \
  _Pragma("unroll") for (int m = 0; m < 8; ++m)                               \
    vv[m] = ((const float4*)(vbuf[P] + 32 * h))[m];                           \
  float a0a = 0.f, a1a = 0.f, a0b = 0.f, a1b = 0.f;                           \
  _Pragma("unroll") for (int m = 0; m < 8; m += 2) {                          \
    { const uint4 W = BUF[m]; const float4 V = vv[m];                         \
      a0a = fmaf(V.x, U0(W.x), a0a); a1a = fmaf(V.x, U1(W.x), a1a);           \
      a0a = fmaf(V.y, U0(W.y), a0a); a1a = fmaf(V.y, U1(W.y), a1a);           \
      a0a = fmaf(V.z, U0(W.z), a0a); a1a = fmaf(V.z, U1(W.z), a1a);           \
      a0a = fmaf(V.w, U0(W.w), a0a); a1a = fmaf(V.w, U1(W.w), a1a); }         \
    { const uint4 W = BUF[m + 1]; const float4 V = vv[m + 1];                 \
      a0b = fmaf(V.x, U0(W.x), a0b); a1b = fmaf(V.x, U1(W.x), a1b);           \
      a0b = fmaf(V.y, U0(W.y), a0b); a1b = fmaf(V.y, U1(W.y), a1b);           \
      a0b = fmaf(V.z, U0(W.z), a0b); a1b = fmaf(V.z, U1(W.z), a1b);           \
      a0b = fmaf(V.w, U0(W.w), a0b); a1b = fmaf(V.w, U1(W.w), a1b); }         \
  }                                                                           \
  float a0 = a0a + a0b, a1 = a1a + a1b;                                       \
  a0 += __shfl_xor(a0, 1, 64);                                                \
  a1 += __shfl_xor(a1, 1, 64);                                                \
  yr = fmaf(s0, yr, fmaf(xc.x, a0, xc.y * a1));                               \
  if (h == 0) vbuf[(P) ^ 1][row] = yr;                                        \
} while (0)

__global__ __launch_bounds__(128, 1) void mps_chain_kernel(
    const float* __restrict__ x,        // [B][S][2]
    const unsigned* __restrict__ etab,  // bf16 pair table
    float* __restrict__ wsv)            // [B][2][64]
{
    __shared__ __align__(16) float vbuf[2][ND];
    __shared__ __align__(16) float xlds[NS * 2];

    const int bid   = blockIdx.x;
    const int batch = bid >> 1;
    const int dir   = bid & 1;
    const int tid   = threadIdx.x;
    const int w     = tid >> 6;
    const int lane  = tid & 63;

    for (int i = tid; i < 98; i += 128)
        ((float4*)xlds)[i] = ((const float4*)(x + batch * (NS * 2)))[i];
    if (tid < 64) vbuf[0][tid] = (tid == 0) ? 1.0f : 0.0f;
    __syncthreads();   // drains prologue vmcnt: our counters start at 0

    if (!dir) {
        const int q = lane >> 4, t = lane & 15;
        const int c0 = 32 * w + 2 * t;
        const char* gLb = (const char*)(etab + 16 * q * 64 + c0);
        float y0r = (c0 == 0) ? 1.f : 0.f, y1r = 0.f;
        uint2 eA[16], eB[16];
        ALOADL(eA, 0); ALOADL(eB, 1);
        #pragma unroll 1
        for (int s = 0; s < 96; s += 2) {
            WAITV(16); LSTEP(0, eA, s);     ALOADL(eA, s + 2); BARRIER();
            WAITV(16); LSTEP(1, eB, s + 1); ALOADL(eB, s + 3); BARRIER();
        }
        WAITV(16); LSTEP(0, eA, 96); BARRIER();
        WAITV(0);  LSTEP(1, eB, 97); BARRIER();   // fully drained
    } else {
        const int lr = lane >> 1, h = lane & 1;
        const int row = 32 * w + lr;
        const char* gRb = (const char*)(etab + row * 64 + 32 * h);
        float yr = (row == 0) ? 1.f : 0.f;
        uint4 rA[8], rB[8];
        ALOADR(rA, 195); ALOADR(rB, 194);
        #pragma unroll 1
        for (int k = 0; k < 96; k += 2) {
            WAITV(8); RSTEP(0, rA, k);     ALOADR(rA, 193 - k); BARRIER();
            WAITV(8); RSTEP(1, rB, k + 1); ALOADR(rB, 192 - k); BARRIER();
        }
        WAITV(8); RSTEP(0, rA, 96); BARRIER();
        WAITV(0); RSTEP(1, rB, 97); BARRIER();    // fully drained
    }
    if (tid < 64) wsv[batch * 128 + dir * 64 + tid] = vbuf[0][tid];
}

__global__ __launch_bounds__(128) void mps_out_kernel(
    const float* __restrict__ wsv,    // [B][2][64]
    const float* __restrict__ oc,     // [O][D][D]
    float* __restrict__ out)          // [B][O]
{
    __shared__ __align__(16) float lsh[ND];
    __shared__ __align__(16) float rsh[ND];
    const int b    = blockIdx.x;
    const int tid  = threadIdx.x;
    const int wave = tid >> 6;
    const int lane = tid & 63;
    if (wave == 0) lsh[lane] = wsv[b * 128 + lane];
    else           rsh[lane] = wsv[b * 128 + 64 + lane];
    __syncthreads();

    #pragma unroll
    for (int oo = 0; oo < 5; ++oo) {
        const int o = wave * 5 + oo;
        const float* ocp = oc + o * (ND * ND) + lane * ND;
        float acc = 0.f;
        #pragma unroll
        for (int t = 0; t < ND; t += 4) {
            const float4 r4 = *(const float4*)(rsh + t);
            const float4 c4 = *(const float4*)(ocp + t);
            acc = fmaf(c4.x, r4.x, acc);
            acc = fmaf(c4.y, r4.y, acc);
            acc = fmaf(c4.z, r4.z, acc);
            acc = fmaf(c4.w, r4.w, acc);
        }
        float p = lsh[lane] * acc;
        #pragma unroll
        for (int off = 32; off > 0; off >>= 1) p += __shfl_xor(p, off, 64);
        if (lane == 0) out[b * NO + o] = p;
    }
}
} // namespace

extern "C" void kernel_launch(void* const* d_in, const int* in_sizes, int n_in,
                              void* d_out, int out_size, void* d_ws, size_t ws_size,
                              hipStream_t stream) {
    const float* x     = (const float*)d_in[0];
    const float* cores = (const float*)d_in[1];
    const float* ocp   = (const float*)d_in[2];
    float* out = (float*)d_out;
    unsigned* etab = (unsigned*)d_ws;
    float* wsv = (float*)((char*)d_ws + EBYTES);
    hipLaunchKernelGGL(mps_conv_kernel,  dim3(EPAIRS / 256), dim3(256), 0, stream, cores, etab);
    hipLaunchKernelGGL(mps_chain_kernel, dim3(2 * NB), dim3(128), 0, stream, x, etab, wsv);
    hipLaunchKernelGGL(mps_out_kernel,   dim3(NB),     dim3(128), 0, stream, wsv, ocp, out);
}